// Round 13
// baseline (583233.691 us; speedup 1.0000x reference)
//
#include <hip/hip_runtime.h>

#define DEV __device__ __forceinline__

typedef _Float16 f16;
typedef _Float16 f16x8 __attribute__((ext_vector_type(8)));
typedef float f32x4 __attribute__((ext_vector_type(4)));

static constexpr int K0P = 416;   // layer0 input dim 400 padded to 13*32
static constexpr int GN  = 3200;  // permuted gate rows = 2*1600 (bijective, no pads)
static constexpr int WK  = 416;   // padded K for Whh rows (13 k-steps of 32)
static constexpr int HSR = 424;   // h_lds row stride in f16 (16B-aligned, 2-way-bank at worst)

// ---------------- math helpers ----------------
DEV float sigf(float x) { return 1.f / (1.f + __expf(-x)); }
DEV float tanhf_(float x) {
  x = fminf(10.f, fmaxf(-10.f, x));
  float e = __expf(2.f * x);
  return (e - 1.f) / (e + 1.f);
}

// row permutation: R in [0,3200): d=R/1600, rr=R%1600, w=rr/112, loc=rr%112,
// t=loc/16, r=loc%16, fq=r>>2, g=r&3  ->  unit u = w*28 + t*4 + fq, gate g.
// (w=14 has exactly 2 tiles: rr 1568..1599 -> u 392..399; clean bijection.)

// ---------------- embedding gather -> x0 f16 [4096][416] ----------------
__global__ void embed_k(const int* __restrict__ wt, const int* __restrict__ pt,
                        const float* __restrict__ we, const float* __restrict__ pe,
                        f16* __restrict__ x0)
{
  const int r = blockIdx.x;
  const int tid = threadIdx.x;
  const int w = wt[r], p = pt[r];
  const float* wrow = we + (size_t)w * 300;
  const float* prow = pe + (size_t)p * 100;
  f16* xr = x0 + (size_t)r * K0P;
  for (int k = tid; k < K0P; k += 128) {
    float v = (k < 300) ? wrow[k] : (k < 400 ? prow[k - 300] : 0.f);
    xr[k] = (f16)v;
  }
}

// ---------------- f32 -> f16 with optional K padding ----------------
__global__ void convpad_k(const float* __restrict__ src, f16* __restrict__ dst,
                          int rows, int K, int KP)
{
  const size_t total = (size_t)rows * KP;
  for (size_t i = (size_t)blockIdx.x * blockDim.x + threadIdx.x; i < total;
       i += (size_t)gridDim.x * blockDim.x) {
    int r = (int)(i / KP), k = (int)(i % KP);
    dst[i] = (f16)(k < K ? src[(size_t)r * K + k] : 0.f);
  }
}

// Wih f32 [2][1600][K] + bias -> permuted f16 [GN][KP] + biasr [GN]
__global__ void wih_reorder_k(const float* __restrict__ src, const float* __restrict__ bias,
                              f16* __restrict__ dst, float* __restrict__ biasr,
                              int K, int KP)
{
  const size_t total = (size_t)GN * KP;
  for (size_t i = (size_t)blockIdx.x * blockDim.x + threadIdx.x; i < total;
       i += (size_t)gridDim.x * blockDim.x) {
    int k = (int)(i % KP);
    int R = (int)(i / KP);
    int d = R / 1600, rr = R % 1600, w = rr / 112, loc = rr % 112;
    int t = loc >> 4, r = loc & 15, fq = r >> 2, g = r & 3;
    int u = w * 28 + t * 4 + fq;
    float v = (k < K) ? src[((size_t)d * 1600 + g * 400 + u) * K + k] : 0.f;
    dst[i] = (f16)v;
    if (k == 0) biasr[R] = bias[d * 1600 + g * 400 + u];
  }
}

// Whh f32 [2][1600][400] -> permuted f16 [2][1600][WK]
__global__ void whh_reorder_k(const float* __restrict__ src, f16* __restrict__ dst)
{
  const int total = 2 * 1600 * WK;
  for (int i = blockIdx.x * blockDim.x + threadIdx.x; i < total;
       i += gridDim.x * blockDim.x) {
    int k = i % WK;
    int R = i / WK;
    int d = R / 1600, rr = R % 1600, w = rr / 112, loc = rr % 112;
    int t = loc >> 4, r = loc & 15, fq = r >> 2, g = r & 3;
    int u = w * 28 + t * 4 + fq;
    float v = (k < 400) ? src[((size_t)d * 1600 + g * 400 + u) * 400 + k] : 0.f;
    dst[i] = (f16)v;
  }
}

__global__ void biascat_k(const float* __restrict__ bh, const float* __restrict__ bm,
                          float* __restrict__ bhm)
{
  int i = threadIdx.x;
  bhm[i] = i < 512 ? bh[i] : bm[i - 512];
}

// ---------------- GEMM: C[M][N] = A[M][KP] * B[N][KP]^T + bias[n] ----------------
__global__ __launch_bounds__(256) void gemm_f16_nt(
    const f16* __restrict__ A, const f16* __restrict__ Bw,
    const float* __restrict__ bias, float* __restrict__ C,
    int M, int N, int KP)
{
  __shared__ __align__(16) f16 As[128][40];
  __shared__ __align__(16) f16 Bs[128][40];
  const int tid = threadIdx.x;
  const int bn = blockIdx.x, bm = blockIdx.y;
  const int lane = tid & 63, wid = tid >> 6;
  const int wr = wid >> 1, wc = wid & 1;
  const int srow = tid >> 1, shalf = tid & 1;
  const f16* Ap = A + (size_t)(bm * 128 + srow) * KP + shalf * 16;
  const f16* Bp = Bw + (size_t)(bn * 128 + srow) * KP + shalf * 16;
  const int fr = lane & 15, fq = lane >> 4;
  f32x4 acc[4][4] = {};
  for (int kt = 0; kt < KP; kt += 32) {
    __syncthreads();
    *(uint4*)&As[srow][shalf * 16]     = *(const uint4*)(Ap + kt);
    *(uint4*)&As[srow][shalf * 16 + 8] = *(const uint4*)(Ap + kt + 8);
    *(uint4*)&Bs[srow][shalf * 16]     = *(const uint4*)(Bp + kt);
    *(uint4*)&Bs[srow][shalf * 16 + 8] = *(const uint4*)(Bp + kt + 8);
    __syncthreads();
    f16x8 af[4], bf[4];
    #pragma unroll
    for (int m = 0; m < 4; ++m) af[m] = *(const f16x8*)&As[wr * 64 + m * 16 + fr][fq * 8];
    #pragma unroll
    for (int n = 0; n < 4; ++n) bf[n] = *(const f16x8*)&Bs[wc * 64 + n * 16 + fr][fq * 8];
    #pragma unroll
    for (int m = 0; m < 4; ++m)
      #pragma unroll
      for (int n = 0; n < 4; ++n)
        acc[m][n] = __builtin_amdgcn_mfma_f32_16x16x32_f16(af[m], bf[n], acc[m][n], 0, 0, 0);
  }
  #pragma unroll
  for (int n = 0; n < 4; ++n) {
    const int gn = bn * 128 + wc * 64 + n * 16 + fr;
    const float bv = bias ? bias[gn] : 0.f;
    #pragma unroll
    for (int m = 0; m < 4; ++m) {
      const size_t gm = (size_t)bm * 128 + wr * 64 + m * 16 + fq * 4;
      #pragma unroll
      for (int r = 0; r < 4; ++r)
        C[(gm + r) * (size_t)N + gn] = acc[m][n][r] + bv;
    }
  }
}

// ---------------- recurrence: 4 blocks = 2 dirs x 2 batch-groups; ZERO comm -----
// Each block owns 16 complete (d,b) chains. Whh lives in VGPRs (distributed over
// 16 waves); h is block-local in LDS (parity double buffer); one barrier/step.
__global__ __launch_bounds__(1024, 1) void lstm_batch_k(
    const float* __restrict__ gates,   // [4096][GN] f32, permuted rows, bias added
    const f16* __restrict__ whh_r,     // [2][1600][WK]
    f16* __restrict__ h_out)           // [4096][800]
{
  __shared__ __align__(16) f16 h_lds[2][16][HSR];

  const int d = blockIdx.x >> 1, bg = blockIdx.x & 1;
  const int tid = threadIdx.x;
  const int lane = tid & 63, w = tid >> 6;
  const int fr = lane & 15, fq = lane >> 4;
  const int ntile = (w < 14) ? 7 : (w == 14 ? 2 : 0);
  const int b = bg * 16 + fr;          // this lane's batch

  // zero both h parity buffers
  {
    uint4 z = {0, 0, 0, 0};
    uint4* hz = (uint4*)h_lds;
    for (int i = tid; i < (int)(sizeof(h_lds) / 16); i += 1024) hz[i] = z;
  }

  // Whh A-fragments -> VGPRs (static indices; 364 regs for 7-tile waves)
  f16x8 wf[7][13];
  {
    const f16* wbase = whh_r + ((size_t)d * 1600 + w * 112 + fr) * WK + fq * 8;
    #pragma unroll
    for (int t = 0; t < 7; ++t)
      #pragma unroll
      for (int kk = 0; kk < 13; ++kk) {
        f16x8 z = {};
        wf[t][kk] = (t < ntile) ? *(const f16x8*)(wbase + (size_t)t * 16 * WK + kk * 32) : z;
      }
  }

  const float* gbase = gates + (size_t)b * 128 * GN + d * 1600 + w * 112 + fq * 4;
  f16* hob = h_out + d * 400;
  float c_[7] = {};
  float4 gp[7];
  {
    const int tt0 = d ? 127 : 0;
    #pragma unroll
    for (int t = 0; t < 7; ++t)
      if (t < ntile) gp[t] = *(const float4*)(gbase + (size_t)tt0 * GN + t * 16);
  }
  __syncthreads();

  for (int s = 0; s < 128; ++s) {
    const int tt = d ? 127 - s : s;
    // g = Whh(regs) @ h(LDS): 91 MFMAs/wave, B-frag shared across tiles
    f32x4 acc[7] = {};
    const f16* hrow = &h_lds[s & 1][fr][fq * 8];
    #pragma unroll
    for (int kk = 0; kk < 13; ++kk) {
      f16x8 bf = *(const f16x8*)(hrow + kk * 32);
      #pragma unroll
      for (int t = 0; t < 7; ++t)
        if (t < ntile)
          acc[t] = __builtin_amdgcn_mfma_f32_16x16x32_f16(wf[t][kk], bf, acc[t], 0, 0, 0);
    }
    // prefetch next step's gates (hidden under act+barrier+next MFMA)
    float4 gn[7];
    #pragma unroll
    for (int t = 0; t < 7; ++t) gn[t] = gp[t];
    if (s < 127) {
      const int tn = d ? 126 - s : s + 1;
      #pragma unroll
      for (int t = 0; t < 7; ++t)
        if (t < ntile) gn[t] = *(const float4*)(gbase + (size_t)tn * GN + t * 16);
    }
    // in-register activations: acc[t][g] = gate g of unit u(t), this lane's batch
    f16* hw = &h_lds[(s & 1) ^ 1][fr][0];
    f16* ho = hob + ((size_t)b * 128 + tt) * 800;
    #pragma unroll
    for (int t = 0; t < 7; ++t)
      if (t < ntile) {
        float vi = acc[t][0] + gp[t].x;
        float vf = acc[t][1] + gp[t].y;
        float vg = acc[t][2] + gp[t].z;
        float vo = acc[t][3] + gp[t].w;
        float c = sigf(vf) * c_[t] + sigf(vi) * tanhf_(vg);
        c_[t] = c;
        f16 h = (f16)(sigf(vo) * tanhf_(c));
        const int u = w * 28 + t * 4 + fq;
        hw[u] = h;
        ho[u] = h;
      }
    #pragma unroll
    for (int t = 0; t < 7; ++t) gp[t] = gn[t];
    __syncthreads();   // h(s) complete in parity buffer; next step reads it
  }
}

// ---------------- tail ----------------
__global__ __launch_bounds__(256) void tail_k(const float* __restrict__ feat,
                                              const float* __restrict__ wo,
                                              float* __restrict__ s_h,
                                              float* __restrict__ s_m)
{
  const int r = blockIdx.x;
  const int tid = threadIdx.x;
  const float* fr = feat + (size_t)r * 1024;
  float sum = 0.f;
  const int n0 = tid * 4;
  #pragma unroll
  for (int j = 0; j < 4; ++j) sum += tanhf_(fr[n0 + j]) * wo[n0 + j];
  #pragma unroll
  for (int off = 32; off > 0; off >>= 1) sum += __shfl_down(sum, off, 64);
  __shared__ float red[4];
  if ((tid & 63) == 0) red[tid >> 6] = sum;
  __syncthreads();
  if (tid == 0)       s_h[r] = red[0] + red[1];
  else if (tid == 64) s_m[r] = red[2] + red[3];
}

__global__ void score_k(const float* __restrict__ s_h, const float* __restrict__ s_m,
                        const float* __restrict__ bo, float* __restrict__ out)
{
  const int bh = blockIdx.x;
  const int m = threadIdx.x;
  out[(size_t)bh * 128 + m] = s_h[bh] + s_m[(bh & ~127) + m] + bo[0];
}

// ---------------- launch ----------------
extern "C" void kernel_launch(void* const* d_in, const int* in_sizes, int n_in,
                              void* d_out, int out_size, void* d_ws, size_t ws_size,
                              hipStream_t stream)
{
  const int*   wt   = (const int*)d_in[0];
  const int*   pt   = (const int*)d_in[2];
  const float* we   = (const float*)d_in[3];
  const float* pe   = (const float*)d_in[4];
  const float* Wih0 = (const float*)d_in[5];
  const float* Whh0 = (const float*)d_in[6];
  const float* b0   = (const float*)d_in[7];
  const float* Wih1 = (const float*)d_in[8];
  const float* Whh1 = (const float*)d_in[9];
  const float* b1   = (const float*)d_in[10];
  const float* Wh   = (const float*)d_in[11];
  const float* bh   = (const float*)d_in[12];
  const float* Wm   = (const float*)d_in[13];
  const float* bm   = (const float*)d_in[14];
  const float* Wo   = (const float*)d_in[15];
  const float* bo   = (const float*)d_in[16];
  float* out = (float*)d_out;

  char* p = (char*)d_ws;
  auto alloc = [&](size_t bytes) { char* q = p; p += (bytes + 255) & ~(size_t)255; return q; };
  f16*   x0    = (f16*)alloc((size_t)4096 * K0P * 2);
  f16*   wihr0 = (f16*)alloc((size_t)GN * K0P * 2);
  f16*   wihr1 = (f16*)alloc((size_t)GN * 800 * 2);
  f16*   whhr0 = (f16*)alloc((size_t)2 * 1600 * WK * 2);
  f16*   whhr1 = (f16*)alloc((size_t)2 * 1600 * WK * 2);
  f16*   whm   = (f16*)alloc((size_t)1024 * 800 * 2);
  float* biasr0= (float*)alloc(GN * 4);
  float* biasr1= (float*)alloc(GN * 4);
  float* bhm   = (float*)alloc(1024 * 4);
  float* sh    = (float*)alloc(4096 * 4);
  float* sm    = (float*)alloc(4096 * 4);
  f16*   h1    = (f16*)alloc((size_t)4096 * 800 * 2);
  f16*   h2    = (f16*)alloc((size_t)4096 * 800 * 2);
  float* gates = (float*)alloc((size_t)4096 * GN * 4);
  float* feat  = (float*)gates;   // gates dead before feature GEMM

  embed_k<<<4096, 128, 0, stream>>>(wt, pt, we, pe, x0);
  wih_reorder_k<<<1024, 256, 0, stream>>>(Wih0, b0, wihr0, biasr0, 400, K0P);
  wih_reorder_k<<<1024, 256, 0, stream>>>(Wih1, b1, wihr1, biasr1, 800, 800);
  whh_reorder_k<<<1024, 256, 0, stream>>>(Whh0, whhr0);
  whh_reorder_k<<<1024, 256, 0, stream>>>(Whh1, whhr1);
  convpad_k<<<1024, 256, 0, stream>>>(Wh, whm, 512, 800, 800);
  convpad_k<<<1024, 256, 0, stream>>>(Wm, whm + (size_t)512 * 800, 512, 800, 800);
  biascat_k<<<1, 1024, 0, stream>>>(bh, bm, bhm);

  // layer 0
  gemm_f16_nt<<<dim3(25, 32), 256, 0, stream>>>(x0, wihr0, biasr0, gates, 4096, GN, K0P);
  lstm_batch_k<<<4, 1024, 0, stream>>>(gates, whhr0, h1);
  // layer 1
  gemm_f16_nt<<<dim3(25, 32), 256, 0, stream>>>(h1, wihr1, biasr1, gates, 4096, GN, 800);
  lstm_batch_k<<<4, 1024, 0, stream>>>(gates, whhr1, h2);
  // features + scorer
  gemm_f16_nt<<<dim3(8, 32), 256, 0, stream>>>(h2, whm, bhm, feat, 4096, 1024, 800);
  tail_k<<<4096, 256, 0, stream>>>(feat, Wo, sh, sm);
  score_k<<<4096, 128, 0, stream>>>(sh, sm, bo, out);
}

// Round 14
// 2122.839 us; speedup vs baseline: 274.7423x; 274.7423x over previous
//
#include <hip/hip_runtime.h>

#define DEV __device__ __forceinline__

typedef _Float16 f16;
typedef _Float16 f16x8 __attribute__((ext_vector_type(8)));
typedef float f32x4 __attribute__((ext_vector_type(4)));
typedef unsigned long long ull;

static constexpr int K0P  = 416;   // layer0 input dim 400 padded to 13*32
static constexpr int NBLK = 13;    // unit-slices per direction (13*32 = 416 >= 400)
static constexpr int GN   = 3328;  // permuted gate cols = 2*13*128
static constexpr int WKP  = 424;   // padded K for Whh rows
static constexpr int HXP  = 13 * 2560;            // per-dir hx bytes ([13][64][40])
static constexpr int SMEM_LSTM = 2 * HXP + 128;   // 66,688 B (hx x2 + flds)
static constexpr int HB1_ELEM  = 2 * 128 * 13 * 1024;  // per-layer hB f16 elems
static constexpr int HB_BYTES  = 2 * HB1_ELEM * 2;
static constexpr unsigned READY0 = 0x80008000u;   // -0.0|-0.0 : exact zero, nonzero bits

// ---------------- math helpers ----------------
DEV float sigf(float x) { return 1.f / (1.f + __expf(-x)); }
DEV float tanhf_(float x) {
  x = fminf(10.f, fmaxf(-10.f, x));
  float e = __expf(2.f * x);
  return (e - 1.f) / (e + 1.f);
}
DEV ull  AL8(const ull* p) { return __hip_atomic_load(p, __ATOMIC_RELAXED, __HIP_MEMORY_SCOPE_AGENT); }
DEV void AS4(unsigned* p, unsigned v) { __hip_atomic_store(p, v, __ATOMIC_RELAXED, __HIP_MEMORY_SCOPE_AGENT); }

// row permutation: loc in [0,128): w=loc>>5, t=(loc>>4)&1, fq=(loc>>2)&3, g=loc&3
// unit u = blk*32 + w*8 + 2*fq + t ; gate g (i,f,g,o)

// ---------------- embedding gather -> x0 f16 [4096][416] ----------------
__global__ void embed_k(const int* __restrict__ wt, const int* __restrict__ pt,
                        const float* __restrict__ we, const float* __restrict__ pe,
                        f16* __restrict__ x0)
{
  const int r = blockIdx.x;
  const int tid = threadIdx.x;
  const int w = wt[r], p = pt[r];
  const float* wrow = we + (size_t)w * 300;
  const float* prow = pe + (size_t)p * 100;
  f16* xr = x0 + (size_t)r * K0P;
  for (int k = tid; k < K0P; k += 128) {
    float v = (k < 300) ? wrow[k] : (k < 400 ? prow[k - 300] : 0.f);
    xr[k] = (f16)v;
  }
}

// ---------------- f32 -> f16 with optional K padding ----------------
__global__ void convpad_k(const float* __restrict__ src, f16* __restrict__ dst,
                          int rows, int K, int KP)
{
  const size_t total = (size_t)rows * KP;
  for (size_t i = (size_t)blockIdx.x * blockDim.x + threadIdx.x; i < total;
       i += (size_t)gridDim.x * blockDim.x) {
    int r = (int)(i / KP), k = (int)(i % KP);
    dst[i] = (f16)(k < K ? src[(size_t)r * K + k] : 0.f);
  }
}

// Wih f32 [2][1600][K] + bias -> permuted f16 [GN][KP] + biasr [GN]
__global__ void wih_reorder_k(const float* __restrict__ src, const float* __restrict__ bias,
                              f16* __restrict__ dst, float* __restrict__ biasr,
                              int K, int KP)
{
  const size_t total = (size_t)GN * KP;
  for (size_t i = (size_t)blockIdx.x * blockDim.x + threadIdx.x; i < total;
       i += (size_t)gridDim.x * blockDim.x) {
    int k = (int)(i % KP);
    int R = (int)(i / KP);
    int d = R / 1664, rr = R % 1664, blk = rr >> 7, loc = rr & 127;
    int w = loc >> 5, t = (loc >> 4) & 1, fq = (loc >> 2) & 3, g = loc & 3;
    int u = blk * 32 + w * 8 + 2 * fq + t;
    float v = (u < 400 && k < K) ? src[((size_t)d * 1600 + g * 400 + u) * K + k] : 0.f;
    dst[i] = (f16)v;
    if (k == 0) biasr[R] = (u < 400) ? bias[d * 1600 + g * 400 + u] : 0.f;
  }
}

// Whh f32 [2][1600][400] -> reordered f16 [2][NBLK][128][WKP]
__global__ void whh_reorder_k(const float* __restrict__ src, f16* __restrict__ dst)
{
  const int total = 2 * NBLK * 128 * WKP;
  for (int i = blockIdx.x * blockDim.x + threadIdx.x; i < total;
       i += gridDim.x * blockDim.x) {
    int k = i % WKP, loc = (i / WKP) & 127, blk = (i / (WKP * 128)) % NBLK,
        d = i / (WKP * 128 * NBLK);
    int w = loc >> 5, t = (loc >> 4) & 1, fq = (loc >> 2) & 3, g = loc & 3;
    int u = blk * 32 + w * 8 + 2 * fq + t;
    float v = (u < 400 && k < 400) ? src[((size_t)d * 1600 + g * 400 + u) * 400 + k] : 0.f;
    dst[i] = (f16)v;
  }
}

__global__ void biascat_k(const float* __restrict__ bh, const float* __restrict__ bm,
                          float* __restrict__ bhm)
{
  int i = threadIdx.x;
  bhm[i] = i < 512 ? bh[i] : bm[i - 512];
}

// hB init (agent-scope stores): zero real slots, READY0 in pad slots (blk 12,
// dword ranges [128,256)+[384,512) per (d,s) slab = units 400..415, never written).
__global__ void init_hb_k(unsigned* __restrict__ p, int n)
{
  for (int i = blockIdx.x * blockDim.x + threadIdx.x; i < n; i += gridDim.x * blockDim.x) {
    int off = i % (13 * 512);
    int blk = off >> 9, win = off & 511;
    bool pad = (blk == 12) && ((win >> 7) & 1);
    AS4(p + i, pad ? READY0 : 0u);
  }
}

// unpack hB (fragment order) -> h_out row-major [4096][800]
__global__ __launch_bounds__(256) void unpack_k(const f16* __restrict__ hBl,
                                                f16* __restrict__ h_out)
{
  const int d = blockIdx.x >> 7, s = blockIdx.x & 127;
  const int t = d ? 127 - s : s;
  const unsigned* slab = (const unsigned*)(hBl + ((size_t)d * 128 + s) * 13 * 1024);
  for (int j = threadIdx.x; j < 13 * 512; j += 256) {
    const int blk = j >> 9, q = j & 511, half = q >> 8, q2 = q & 255;
    const int fq = q2 & 3, fr = (q2 >> 2) & 15, w = q2 >> 6;
    const int u0 = blk * 32 + w * 8 + 2 * fq;
    if (u0 < 400) {
      const int b = fr + 16 * half;
      *(unsigned*)(h_out + (size_t)(b * 128 + t) * 800 + d * 400 + u0) = slab[j];
    }
  }
}

// ---------------- GEMM: C[M][N] = A[M][KP] * B[N][KP]^T + bias[n] ----------------
__global__ __launch_bounds__(256) void gemm_f16_nt(
    const f16* __restrict__ A, const f16* __restrict__ Bw,
    const float* __restrict__ bias, float* __restrict__ C,
    int M, int N, int KP)
{
  __shared__ __align__(16) f16 As[128][40];
  __shared__ __align__(16) f16 Bs[128][40];
  const int tid = threadIdx.x;
  const int bn = blockIdx.x, bm = blockIdx.y;
  const int lane = tid & 63, wid = tid >> 6;
  const int wr = wid >> 1, wc = wid & 1;
  const int srow = tid >> 1, shalf = tid & 1;
  const f16* Ap = A + (size_t)(bm * 128 + srow) * KP + shalf * 16;
  const f16* Bp = Bw + (size_t)(bn * 128 + srow) * KP + shalf * 16;
  const int fr = lane & 15, fq = lane >> 4;
  f32x4 acc[4][4] = {};
  for (int kt = 0; kt < KP; kt += 32) {
    __syncthreads();
    *(uint4*)&As[srow][shalf * 16]     = *(const uint4*)(Ap + kt);
    *(uint4*)&As[srow][shalf * 16 + 8] = *(const uint4*)(Ap + kt + 8);
    *(uint4*)&Bs[srow][shalf * 16]     = *(const uint4*)(Bp + kt);
    *(uint4*)&Bs[srow][shalf * 16 + 8] = *(const uint4*)(Bp + kt + 8);
    __syncthreads();
    f16x8 af[4], bf[4];
    #pragma unroll
    for (int m = 0; m < 4; ++m) af[m] = *(const f16x8*)&As[wr * 64 + m * 16 + fr][fq * 8];
    #pragma unroll
    for (int n = 0; n < 4; ++n) bf[n] = *(const f16x8*)&Bs[wc * 64 + n * 16 + fr][fq * 8];
    #pragma unroll
    for (int m = 0; m < 4; ++m)
      #pragma unroll
      for (int n = 0; n < 4; ++n)
        acc[m][n] = __builtin_amdgcn_mfma_f32_16x16x32_f16(af[m], bf[n], acc[m][n], 0, 0, 0);
  }
  #pragma unroll
  for (int n = 0; n < 4; ++n) {
    const int gn = bn * 128 + wc * 64 + n * 16 + fr;
    const float bv = bias ? bias[gn] : 0.f;
    #pragma unroll
    for (int m = 0; m < 4; ++m) {
      const size_t gm = (size_t)bm * 128 + wr * 64 + m * 16 + fq * 4;
      #pragma unroll
      for (int r = 0; r < 4; ++r)
        C[(gm + r) * (size_t)N + gn] = acc[m][n][r] + bv;
    }
  }
}

// ---------------- recurrence: 13 blocks, BOTH dirs fused per block --------------
// Phase F (fwd) then phase B (bwd) per step: each handoff's visibility latency
// hides under the other direction's compute. W for both dirs in VGPRs (208 regs).
// hB [d][s][blk][1024] f16 (pads READY0); hx single buffer per dir; flds monotonic.
__global__ __launch_bounds__(256, 1) void lstm_dual_k(
    const float* __restrict__ gates,
    const f16* __restrict__ whh_r,
    f16* __restrict__ hB)
{
  extern __shared__ __align__(16) char smem[];
  char* hx0  = smem;                     // [13][64][40] dir 0
  char* hx1  = smem + HXP;               // [13][64][40] dir 1
  int*  flds = (int*)(smem + 2 * HXP);   // [2][16] monotonic staged-step counters

  const int blk = blockIdx.x;
  const int tid = threadIdx.x;
  const int lane = tid & 63, w = tid >> 6;
  const int fr = lane & 15, fq = lane >> 4;

  if (tid < 32) flds[tid] = -1;

  // W A-fragments for both dirs -> VGPRs (static indices after unroll)
  f16x8 af[2][2][13];
  #pragma unroll
  for (int dd = 0; dd < 2; ++dd) {
    const f16* wr0 = whh_r + ((size_t)(dd * NBLK + blk) * 128 + w * 32 + fr) * WKP + fq * 8;
    #pragma unroll
    for (int kk = 0; kk < 13; ++kk) {
      af[dd][0][kk] = *(const f16x8*)(wr0 + kk * 32);
      af[dd][1][kk] = *(const f16x8*)(wr0 + (size_t)16 * WKP + kk * 32);
    }
  }

  const int u0 = blk * 32 + w * 8 + 2 * fq;   // even; u1 = u0+1
  const bool ok = u0 < 400;
  const int nkk = (w == 0) ? 4 : 3;           // poll partition {4,3,3,3}
  const int kk0 = (w == 0) ? 0 : 4 + 3 * (w - 1);
  const unsigned ownfull = (1u << nkk) - 1;

  const float* gb[2][2];
  #pragma unroll
  for (int dd = 0; dd < 2; ++dd) {
    gb[dd][0] = gates + (size_t)(fr * 128) * GN + dd * 1664 + blk * 128 + w * 32;
    gb[dd][1] = gb[dd][0] + (size_t)16 * 128 * GN;
  }
  float  c_[2][4] = {};
  float4 gp[2][4];
  #pragma unroll
  for (int dd = 0; dd < 2; ++dd) {
    const int t0 = dd ? 127 : 0;
    gp[dd][0] = *(const float4*)(gb[dd][0] + (size_t)t0 * GN + fq * 4);        // (u0,  b=fr)
    gp[dd][1] = *(const float4*)(gb[dd][0] + (size_t)t0 * GN + 16 + fq * 4);   // (u0+1,b=fr)
    gp[dd][2] = *(const float4*)(gb[dd][1] + (size_t)t0 * GN + fq * 4);        // (u0,  b=fr+16)
    gp[dd][3] = *(const float4*)(gb[dd][1] + (size_t)t0 * GN + 16 + fq * 4);   // (u0+1,b=fr+16)
  }
  __syncthreads();

  for (int s = 0; s < 128; ++s) {
    #pragma unroll
    for (int dd = 0; dd < 2; ++dd) {
      char* hxw = dd ? hx1 : hx0;
      int*  fld = flds + dd * 16;
      f32x4 acc00 = {}, acc01 = {}, acc10 = {}, acc11 = {};
      if (s > 0) {
        // poll own kk subset from hB[dd][s-1]; stage to LDS; flag; spin for all 13
        const ull* slab = (const ull*)(hB + ((size_t)dd * 128 + (s - 1)) * 13 * 1024) + lane * 2;
        ull q[4][4];
        unsigned pend = (nkk == 4) ? 0xFFFFu : 0x0FFFu;
        unsigned stagedm = 0, flagged = 0;
        int rnd = 0;
        while (flagged != ownfull) {
          #pragma unroll
          for (int i = 0; i < 4; ++i)
            if (i < nkk && !((flagged >> i) & 1)) {
              const ull* pp = slab + (kk0 + i) * 256;
              if ((pend >> (i * 4 + 0)) & 1) q[i][0] = AL8(pp);
              if ((pend >> (i * 4 + 1)) & 1) q[i][1] = AL8(pp + 1);
              if ((pend >> (i * 4 + 2)) & 1) q[i][2] = AL8(pp + 128);
              if ((pend >> (i * 4 + 3)) & 1) q[i][3] = AL8(pp + 129);
            }
          __builtin_amdgcn_sched_barrier(0);   // keep loads issued before checks
          #pragma unroll
          for (int i = 0; i < 4; ++i)
            if (i < nkk && !((flagged >> i) & 1)) {
              #pragma unroll
              for (int j = 0; j < 4; ++j)
                if ((pend >> (i * 4 + j)) & 1) {
                  ull v = q[i][j];
                  if ((unsigned)v != 0u && (unsigned)(v >> 32) != 0u)
                    pend &= ~(1u << (i * 4 + j));
                }
              if (!((stagedm >> i) & 1) && ((pend >> (i * 4)) & 15u) == 0u) {
                char* hp = hxw + (kk0 + i) * 2560 + lane * 40;
                *(ull*)(hp +  0) = q[i][0];
                *(ull*)(hp +  8) = q[i][1];
                *(ull*)(hp + 16) = q[i][2];
                *(ull*)(hp + 24) = q[i][3];
                stagedm |= 1u << i;
              }
              bool dn = (stagedm >> i) & 1;
              if (__all(dn)) {
                asm volatile("s_waitcnt lgkmcnt(0)" ::: "memory");
                if (lane == 0)
                  __hip_atomic_store(&fld[kk0 + i], s, __ATOMIC_RELAXED,
                                     __HIP_MEMORY_SCOPE_WORKGROUP);
                flagged |= 1u << i;
              }
            }
          if (flagged != ownfull && ++rnd >= 2) __builtin_amdgcn_s_sleep(1);
        }
        // wait for all 13 kk staged (intra-CU spin over monotonic counters)
        for (;;) {
          int fv = (lane < 13)
                     ? __hip_atomic_load(&fld[lane], __ATOMIC_RELAXED,
                                         __HIP_MEMORY_SCOPE_WORKGROUP)
                     : 0x7fffffff;
          if (!__any(fv < s)) break;
          __builtin_amdgcn_s_sleep(1);
        }
        asm volatile("" ::: "memory");
        // 52 MFMAs with A from VGPRs, B from LDS
        #pragma unroll
        for (int kk = 0; kk < 13; ++kk) {
          const char* hp = hxw + kk * 2560 + lane * 40;
          union { ull u[2]; f16x8 v; } B0, B1;
          B0.u[0] = *(const ull*)(hp);      B0.u[1] = *(const ull*)(hp + 8);
          B1.u[0] = *(const ull*)(hp + 16); B1.u[1] = *(const ull*)(hp + 24);
          acc00 = __builtin_amdgcn_mfma_f32_16x16x32_f16(af[dd][0][kk], B0.v, acc00, 0, 0, 0);
          acc01 = __builtin_amdgcn_mfma_f32_16x16x32_f16(af[dd][0][kk], B1.v, acc01, 0, 0, 0);
          acc10 = __builtin_amdgcn_mfma_f32_16x16x32_f16(af[dd][1][kk], B0.v, acc10, 0, 0, 0);
          acc11 = __builtin_amdgcn_mfma_f32_16x16x32_f16(af[dd][1][kk], B1.v, acc11, 0, 0, 0);
        }
      }

      // consume current gates, prefetch next step's (flight hides under next phase)
      float4 g0 = gp[dd][0], g1 = gp[dd][1], g2 = gp[dd][2], g3 = gp[dd][3];
      if (s < 127) {
        const int tn = dd ? 126 - s : s + 1;
        gp[dd][0] = *(const float4*)(gb[dd][0] + (size_t)tn * GN + fq * 4);
        gp[dd][1] = *(const float4*)(gb[dd][0] + (size_t)tn * GN + 16 + fq * 4);
        gp[dd][2] = *(const float4*)(gb[dd][1] + (size_t)tn * GN + fq * 4);
        gp[dd][3] = *(const float4*)(gb[dd][1] + (size_t)tn * GN + 16 + fq * 4);
      }

      auto act = [&](const f32x4& a, const float4& p, float& c) -> f16 {
        float vi = a[0] + p.x, vf = a[1] + p.y, vg = a[2] + p.z, vo = a[3] + p.w;
        c = sigf(vf) * c + sigf(vi) * tanhf_(vg);
        return (f16)(sigf(vo) * tanhf_(c));
      };
      f16 h00 = act(acc00, g0, c_[dd][0]);   // (u0,   batch fr)
      f16 h10 = act(acc10, g1, c_[dd][1]);   // (u0+1, batch fr)
      f16 h01 = act(acc01, g2, c_[dd][2]);   // (u0,   batch fr+16)
      f16 h11 = act(acc11, g3, c_[dd][3]);   // (u0+1, batch fr+16)

      if (ok) {
        unsigned pk0 = (unsigned)__builtin_bit_cast(unsigned short, h00) |
                       ((unsigned)__builtin_bit_cast(unsigned short, h10) << 16);
        unsigned pk1 = (unsigned)__builtin_bit_cast(unsigned short, h01) |
                       ((unsigned)__builtin_bit_cast(unsigned short, h11) << 16);
        if (pk0 == 0u) pk0 = READY0;
        if (pk1 == 0u) pk1 = READY0;
        unsigned* hbw = (unsigned*)(hB + ((size_t)dd * 128 + s) * 13 * 1024 + blk * 1024
                                    + (w * 16 + fr) * 8) + fq;
        AS4(hbw, pk0);
        AS4(hbw + 256, pk1);
      }
      __syncthreads();   // all hx[dd] reads done; next overwrite is a full step away
    }
  }
}

// ---------------- tail ----------------
__global__ __launch_bounds__(256) void tail_k(const float* __restrict__ feat,
                                              const float* __restrict__ wo,
                                              float* __restrict__ s_h,
                                              float* __restrict__ s_m)
{
  const int r = blockIdx.x;
  const int tid = threadIdx.x;
  const float* fr = feat + (size_t)r * 1024;
  float sum = 0.f;
  const int n0 = tid * 4;
  #pragma unroll
  for (int j = 0; j < 4; ++j) sum += tanhf_(fr[n0 + j]) * wo[n0 + j];
  #pragma unroll
  for (int off = 32; off > 0; off >>= 1) sum += __shfl_down(sum, off, 64);
  __shared__ float red[4];
  if ((tid & 63) == 0) red[tid >> 6] = sum;
  __syncthreads();
  if (tid == 0)       s_h[r] = red[0] + red[1];
  else if (tid == 64) s_m[r] = red[2] + red[3];
}

__global__ void score_k(const float* __restrict__ s_h, const float* __restrict__ s_m,
                        const float* __restrict__ bo, float* __restrict__ out)
{
  const int bh = blockIdx.x;
  const int m = threadIdx.x;
  out[(size_t)bh * 128 + m] = s_h[bh] + s_m[(bh & ~127) + m] + bo[0];
}

// ---------------- launch ----------------
extern "C" void kernel_launch(void* const* d_in, const int* in_sizes, int n_in,
                              void* d_out, int out_size, void* d_ws, size_t ws_size,
                              hipStream_t stream)
{
  const int*   wt   = (const int*)d_in[0];
  const int*   pt   = (const int*)d_in[2];
  const float* we   = (const float*)d_in[3];
  const float* pe   = (const float*)d_in[4];
  const float* Wih0 = (const float*)d_in[5];
  const float* Whh0 = (const float*)d_in[6];
  const float* b0   = (const float*)d_in[7];
  const float* Wih1 = (const float*)d_in[8];
  const float* Whh1 = (const float*)d_in[9];
  const float* b1   = (const float*)d_in[10];
  const float* Wh   = (const float*)d_in[11];
  const float* bh   = (const float*)d_in[12];
  const float* Wm   = (const float*)d_in[13];
  const float* bm   = (const float*)d_in[14];
  const float* Wo   = (const float*)d_in[15];
  const float* bo   = (const float*)d_in[16];
  float* out = (float*)d_out;

  char* p = (char*)d_ws;
  auto alloc = [&](size_t bytes) { char* q = p; p += (bytes + 255) & ~(size_t)255; return q; };
  f16*   x0    = (f16*)alloc((size_t)4096 * K0P * 2);
  f16*   wihr0 = (f16*)alloc((size_t)GN * K0P * 2);
  f16*   wihr1 = (f16*)alloc((size_t)GN * 800 * 2);
  f16*   whhr0 = (f16*)alloc((size_t)2 * NBLK * 128 * WKP * 2);
  f16*   whhr1 = (f16*)alloc((size_t)2 * NBLK * 128 * WKP * 2);
  f16*   whm   = (f16*)alloc((size_t)1024 * 800 * 2);
  float* biasr0= (float*)alloc(GN * 4);
  float* biasr1= (float*)alloc(GN * 4);
  float* bhm   = (float*)alloc(1024 * 4);
  float* sh    = (float*)alloc(4096 * 4);
  float* sm    = (float*)alloc(4096 * 4);
  f16*   h1    = (f16*)alloc((size_t)4096 * 800 * 2);
  f16*   h2    = (f16*)alloc((size_t)4096 * 800 * 2);
  f16*   hB    = (f16*)alloc(HB_BYTES);          // [layer][d][s][blk][1024]
  float* gates = (float*)alloc((size_t)4096 * GN * 4);
  float* feat  = (float*)gates;   // gates dead before feature GEMM

  static bool attr_set = false;
  if (!attr_set) {
    hipFuncSetAttribute((const void*)lstm_dual_k,
                        hipFuncAttributeMaxDynamicSharedMemorySize, SMEM_LSTM);
    attr_set = true;
  }

  init_hb_k<<<512, 256, 0, stream>>>((unsigned*)hB, HB_BYTES / 4);
  embed_k<<<4096, 128, 0, stream>>>(wt, pt, we, pe, x0);
  wih_reorder_k<<<1024, 256, 0, stream>>>(Wih0, b0, wihr0, biasr0, 400, K0P);
  wih_reorder_k<<<1024, 256, 0, stream>>>(Wih1, b1, wihr1, biasr1, 800, 800);
  whh_reorder_k<<<1024, 256, 0, stream>>>(Whh0, whhr0);
  whh_reorder_k<<<1024, 256, 0, stream>>>(Whh1, whhr1);
  convpad_k<<<1024, 256, 0, stream>>>(Wh, whm, 512, 800, 800);
  convpad_k<<<1024, 256, 0, stream>>>(Wm, whm + (size_t)512 * 800, 512, 800, 800);
  biascat_k<<<1, 1024, 0, stream>>>(bh, bm, bhm);

  // layer 0
  gemm_f16_nt<<<dim3(26, 32), 256, 0, stream>>>(x0, wihr0, biasr0, gates, 4096, GN, K0P);
  lstm_dual_k<<<NBLK, 256, SMEM_LSTM, stream>>>(gates, whhr0, hB);
  unpack_k<<<256, 256, 0, stream>>>(hB, h1);
  // layer 1
  gemm_f16_nt<<<dim3(26, 32), 256, 0, stream>>>(h1, wihr1, biasr1, gates, 4096, GN, 800);
  lstm_dual_k<<<NBLK, 256, SMEM_LSTM, stream>>>(gates, whhr1, hB + HB1_ELEM);
  unpack_k<<<256, 256, 0, stream>>>(hB + HB1_ELEM, h2);
  // features + scorer
  gemm_f16_nt<<<dim3(8, 32), 256, 0, stream>>>(h2, whm, bhm, feat, 4096, 1024, 800);
  tail_k<<<4096, 256, 0, stream>>>(feat, Wo, sh, sm);
  score_k<<<4096, 128, 0, stream>>>(sh, sm, bo, out);
}

// Round 15
// 1522.306 us; speedup vs baseline: 383.1250x; 1.3945x over previous
//
#include <hip/hip_runtime.h>

#define DEV __device__ __forceinline__

typedef _Float16 f16;
typedef _Float16 f16x8 __attribute__((ext_vector_type(8)));
typedef float f32x4 __attribute__((ext_vector_type(4)));
typedef unsigned long long ull;

static constexpr int K0P  = 416;   // layer0 input dim 400 padded to 13*32
static constexpr int NBLK = 7;     // unit-slices per direction (7*64 = 448 >= 400)
static constexpr int GN   = 3584;  // permuted gate cols = 2*7*256
static constexpr int WKP  = 424;   // padded K for Whh rows
static constexpr int HXB  = 13 * 2560;           // hx bytes ([13][64][40])
static constexpr int SMEM_LSTM = HXB + 64;       // 33,344 B
static constexpr int HB1_ELEM  = 2 * 128 * 13 * 1024;  // per-layer hB f16 elems
static constexpr int HB_BYTES  = 2 * HB1_ELEM * 2;
static constexpr unsigned short RDY = 0x8000;    // -0.0 : exact zero, nonzero bits

// ---------------- math helpers ----------------
DEV float sigf(float x) { return 1.f / (1.f + __expf(-x)); }
DEV float tanhf_(float x) {
  x = fminf(10.f, fmaxf(-10.f, x));
  float e = __expf(2.f * x);
  return (e - 1.f) / (e + 1.f);
}
DEV ull  AL8(const ull* p) { return __hip_atomic_load(p, __ATOMIC_RELAXED, __HIP_MEMORY_SCOPE_AGENT); }
DEV void AS8(ull* p, ull v) { __hip_atomic_store(p, v, __ATOMIC_RELAXED, __HIP_MEMORY_SCOPE_AGENT); }
DEV void AS4(unsigned* p, unsigned v) { __hip_atomic_store(p, v, __ATOMIC_RELAXED, __HIP_MEMORY_SCOPE_AGENT); }

// row permutation: loc in [0,256): w=loc>>6, t=(loc>>4)&3, fq=(loc>>2)&3, g=loc&3
// unit u = blk*64 + w*16 + fq*4 + t ; gate g (i,f,g,o). Lane (w,fq) owns 4
// consecutive units u0..u0+3 (t=0..3) -> one 8B qword per publish half.

// ---------------- embedding gather -> x0 f16 [4096][416] ----------------
__global__ void embed_k(const int* __restrict__ wt, const int* __restrict__ pt,
                        const float* __restrict__ we, const float* __restrict__ pe,
                        f16* __restrict__ x0)
{
  const int r = blockIdx.x;
  const int tid = threadIdx.x;
  const int w = wt[r], p = pt[r];
  const float* wrow = we + (size_t)w * 300;
  const float* prow = pe + (size_t)p * 100;
  f16* xr = x0 + (size_t)r * K0P;
  for (int k = tid; k < K0P; k += 128) {
    float v = (k < 300) ? wrow[k] : (k < 400 ? prow[k - 300] : 0.f);
    xr[k] = (f16)v;
  }
}

// ---------------- f32 -> f16 with optional K padding ----------------
__global__ void convpad_k(const float* __restrict__ src, f16* __restrict__ dst,
                          int rows, int K, int KP)
{
  const size_t total = (size_t)rows * KP;
  for (size_t i = (size_t)blockIdx.x * blockDim.x + threadIdx.x; i < total;
       i += (size_t)gridDim.x * blockDim.x) {
    int r = (int)(i / KP), k = (int)(i % KP);
    dst[i] = (f16)(k < K ? src[(size_t)r * K + k] : 0.f);
  }
}

// Wih f32 [2][1600][K] + bias -> permuted f16 [GN][KP] + biasr [GN]
__global__ void wih_reorder_k(const float* __restrict__ src, const float* __restrict__ bias,
                              f16* __restrict__ dst, float* __restrict__ biasr,
                              int K, int KP)
{
  const size_t total = (size_t)GN * KP;
  for (size_t i = (size_t)blockIdx.x * blockDim.x + threadIdx.x; i < total;
       i += (size_t)gridDim.x * blockDim.x) {
    int k = (int)(i % KP);
    int R = (int)(i / KP);
    int d = R / 1792, rr = R % 1792, blk = rr >> 8, loc = rr & 255;
    int w = loc >> 6, t = (loc >> 4) & 3, fq = (loc >> 2) & 3, g = loc & 3;
    int u = blk * 64 + w * 16 + fq * 4 + t;
    float v = (u < 400 && k < K) ? src[((size_t)d * 1600 + g * 400 + u) * K + k] : 0.f;
    dst[i] = (f16)v;
    if (k == 0) biasr[R] = (u < 400) ? bias[d * 1600 + g * 400 + u] : 0.f;
  }
}

// Whh f32 [2][1600][400] -> reordered f16 [2][NBLK][256][WKP]
__global__ void whh_reorder_k(const float* __restrict__ src, f16* __restrict__ dst)
{
  const int total = 2 * NBLK * 256 * WKP;
  for (int i = blockIdx.x * blockDim.x + threadIdx.x; i < total;
       i += gridDim.x * blockDim.x) {
    int k = i % WKP, loc = (i / WKP) & 255, blk = (i / (WKP * 256)) % NBLK,
        d = i / (WKP * 256 * NBLK);
    int w = loc >> 6, t = (loc >> 4) & 3, fq = (loc >> 2) & 3, g = loc & 3;
    int u = blk * 64 + w * 16 + fq * 4 + t;
    float v = (u < 400 && k < 400) ? src[((size_t)d * 1600 + g * 400 + u) * 400 + k] : 0.f;
    dst[i] = (f16)v;
  }
}

__global__ void biascat_k(const float* __restrict__ bh, const float* __restrict__ bm,
                          float* __restrict__ bhm)
{
  int i = threadIdx.x;
  bhm[i] = i < 512 ? bh[i] : bm[i - 512];
}

// hB init (agent-scope): zero real slots, RDY pairs in pad slots (slab 12,
// dword win with (win>>7)&1 per 512-dword slab = units 400..415, never written).
__global__ void init_hb_k(unsigned* __restrict__ p, int n)
{
  for (int i = blockIdx.x * blockDim.x + threadIdx.x; i < n; i += gridDim.x * blockDim.x) {
    int off = i % (13 * 512);
    int kk = off >> 9, win = off & 511;
    bool pad = (kk == 12) && ((win >> 7) & 1);
    AS4(p + i, pad ? 0x80008000u : 0u);
  }
}

// unpack hB (fragment order) -> h_out row-major [4096][800]
__global__ __launch_bounds__(256) void unpack_k(const f16* __restrict__ hBl,
                                                f16* __restrict__ h_out)
{
  const int d = blockIdx.x >> 7, s = blockIdx.x & 127;
  const int t = d ? 127 - s : s;
  const unsigned* slab = (const unsigned*)(hBl + ((size_t)d * 128 + s) * 13 * 1024);
  for (int dj = threadIdx.x; dj < 13 * 512; dj += 256) {
    const int kk = dj / 512, r = dj % 512;
    const int half = r >> 8, r2 = r & 255;
    const int fqc = r2 >> 6, fr = (r2 >> 2) & 15, e = (r2 & 3) * 2;
    const int u = kk * 32 + fqc * 8 + e;
    if (u < 400) {
      const int b = fr + 16 * half;
      *(unsigned*)(h_out + (size_t)(b * 128 + t) * 800 + d * 400 + u) = slab[dj];
    }
  }
}

// ---------------- GEMM: C[M][N] = A[M][KP] * B[N][KP]^T + bias[n] ----------------
__global__ __launch_bounds__(256) void gemm_f16_nt(
    const f16* __restrict__ A, const f16* __restrict__ Bw,
    const float* __restrict__ bias, float* __restrict__ C,
    int M, int N, int KP)
{
  __shared__ __align__(16) f16 As[128][40];
  __shared__ __align__(16) f16 Bs[128][40];
  const int tid = threadIdx.x;
  const int bn = blockIdx.x, bm = blockIdx.y;
  const int lane = tid & 63, wid = tid >> 6;
  const int wr = wid >> 1, wc = wid & 1;
  const int srow = tid >> 1, shalf = tid & 1;
  const f16* Ap = A + (size_t)(bm * 128 + srow) * KP + shalf * 16;
  const f16* Bp = Bw + (size_t)(bn * 128 + srow) * KP + shalf * 16;
  const int fr = lane & 15, fq = lane >> 4;
  f32x4 acc[4][4] = {};
  for (int kt = 0; kt < KP; kt += 32) {
    __syncthreads();
    *(uint4*)&As[srow][shalf * 16]     = *(const uint4*)(Ap + kt);
    *(uint4*)&As[srow][shalf * 16 + 8] = *(const uint4*)(Ap + kt + 8);
    *(uint4*)&Bs[srow][shalf * 16]     = *(const uint4*)(Bp + kt);
    *(uint4*)&Bs[srow][shalf * 16 + 8] = *(const uint4*)(Bp + kt + 8);
    __syncthreads();
    f16x8 af[4], bf[4];
    #pragma unroll
    for (int m = 0; m < 4; ++m) af[m] = *(const f16x8*)&As[wr * 64 + m * 16 + fr][fq * 8];
    #pragma unroll
    for (int n = 0; n < 4; ++n) bf[n] = *(const f16x8*)&Bs[wc * 64 + n * 16 + fr][fq * 8];
    #pragma unroll
    for (int m = 0; m < 4; ++m)
      #pragma unroll
      for (int n = 0; n < 4; ++n)
        acc[m][n] = __builtin_amdgcn_mfma_f32_16x16x32_f16(af[m], bf[n], acc[m][n], 0, 0, 0);
  }
  #pragma unroll
  for (int n = 0; n < 4; ++n) {
    const int gn = bn * 128 + wc * 64 + n * 16 + fr;
    const float bv = bias ? bias[gn] : 0.f;
    #pragma unroll
    for (int m = 0; m < 4; ++m) {
      const size_t gm = (size_t)bm * 128 + wr * 64 + m * 16 + fq * 4;
      #pragma unroll
      for (int r = 0; r < 4; ++r)
        C[(gm + r) * (size_t)N + gn] = acc[m][n][r] + bv;
    }
  }
}

// ---------------- recurrence: 14 blocks = 2 dirs x 7 slices -------------------
// W in VGPRs (52 f16x8). Publish = one 8B atomic qword per half (all-or-nothing
// => poll check is a single v!=0). hB [d][s][13 kk][1024] f16; pads born-ready.
__global__ __launch_bounds__(256, 1) void lstm_mfma_k(
    const float* __restrict__ gates,
    const f16* __restrict__ whh_r,
    f16* __restrict__ hB)
{
  extern __shared__ __align__(16) char smem[];
  char* hx   = smem;                 // [13][64][40]
  int*  flds = (int*)(smem + HXB);   // [16] monotonic staged-step counters

  const int d = blockIdx.x / NBLK, blk = blockIdx.x % NBLK;
  const int tid = threadIdx.x;
  const int lane = tid & 63, w = tid >> 6;
  const int fr = lane & 15, fq = lane >> 4;

  if (tid < 16) flds[tid] = -1;

  // W A-fragments -> VGPRs (static indices; 208 regs)
  f16x8 af[4][13];
  {
    const f16* wbase = whh_r + ((size_t)(d * NBLK + blk) * 256 + w * 64 + fr) * WKP + fq * 8;
    #pragma unroll
    for (int t = 0; t < 4; ++t)
      #pragma unroll
      for (int kk = 0; kk < 13; ++kk)
        af[t][kk] = *(const f16x8*)(wbase + (size_t)t * 16 * WKP + kk * 32);
  }

  const int u0 = blk * 64 + w * 16 + fq * 4;   // units u0..u0+3
  const bool ok = u0 < 400;
  // gates: col base for (t): d*1792 + blk*256 + w*64 + t*16 + fq*4
  const float* gb0 = gates + (size_t)(fr * 128) * GN + d * 1792 + blk * 256 + w * 64 + fq * 4;
  const float* gb1 = gb0 + (size_t)16 * 128 * GN;
  // publish qword position
  const int kkp  = 2 * blk + (w >> 1);
  const int fqc  = (w & 1) * 2 + (fq >> 1);
  const int qidx = (fqc * 16 + fr) * 2 + (fq & 1);
  const int nkk = (w == 0) ? 4 : 3;            // poll partition {4,3,3,3}
  const int kk0 = (w == 0) ? 0 : 4 + 3 * (w - 1);
  const unsigned full = (1u << nkk) - 1;

  float c_[4][2] = {};
  __syncthreads();

  for (int s = 0; s < 128; ++s) {
    const int tt = d ? 127 - s : s;
    // current-step gates (issued before poll; flight hides under poll rounds)
    float4 g0[4], g1[4];
    #pragma unroll
    for (int t = 0; t < 4; ++t) {
      g0[t] = *(const float4*)(gb0 + (size_t)tt * GN + t * 16);
      g1[t] = *(const float4*)(gb1 + (size_t)tt * GN + t * 16);
    }

    f32x4 acc[4][2] = {};
    if (s > 0) {
      const ull* slab = (const ull*)(hB + ((size_t)d * 128 + (s - 1)) * 13 * 1024) + lane * 2;
      ull q[4][4];
      unsigned pend = (nkk == 4) ? 0xFFFFu : 0x0FFFu;
      unsigned stagedm = 0, flagged = 0;
      int rnd = 0;
      while (flagged != full) {
        #pragma unroll
        for (int i = 0; i < 4; ++i)
          if (i < nkk && !((flagged >> i) & 1)) {
            const ull* pp = slab + (kk0 + i) * 256;
            if ((pend >> (i * 4 + 0)) & 1) q[i][0] = AL8(pp);
            if ((pend >> (i * 4 + 1)) & 1) q[i][1] = AL8(pp + 1);
            if ((pend >> (i * 4 + 2)) & 1) q[i][2] = AL8(pp + 128);
            if ((pend >> (i * 4 + 3)) & 1) q[i][3] = AL8(pp + 129);
          }
        __builtin_amdgcn_sched_barrier(0);   // keep loads issued before checks
        #pragma unroll
        for (int i = 0; i < 4; ++i)
          if (i < nkk && !((flagged >> i) & 1)) {
            #pragma unroll
            for (int j = 0; j < 4; ++j)
              if (((pend >> (i * 4 + j)) & 1) && q[i][j] != 0ull)
                pend &= ~(1u << (i * 4 + j));   // 8B store is all-or-nothing
            if (!((stagedm >> i) & 1) && ((pend >> (i * 4)) & 15u) == 0u) {
              char* hp = hx + (kk0 + i) * 2560 + lane * 40;
              *(ull*)(hp +  0) = q[i][0];
              *(ull*)(hp +  8) = q[i][1];
              *(ull*)(hp + 16) = q[i][2];
              *(ull*)(hp + 24) = q[i][3];
              stagedm |= 1u << i;
            }
            bool dn = (stagedm >> i) & 1;
            if (__all(dn)) {
              asm volatile("s_waitcnt lgkmcnt(0)" ::: "memory");
              if (lane == 0)
                __hip_atomic_store(&flds[kk0 + i], s, __ATOMIC_RELAXED,
                                   __HIP_MEMORY_SCOPE_WORKGROUP);
              flagged |= 1u << i;
            }
          }
        if (flagged != full && ++rnd >= 2) __builtin_amdgcn_s_sleep(1);
      }
      // wait for all 13 kk staged (intra-CU spin, acquire orders hx reads)
      for (;;) {
        int fv = (lane < 13)
                   ? __hip_atomic_load(&flds[lane], __ATOMIC_ACQUIRE,
                                       __HIP_MEMORY_SCOPE_WORKGROUP)
                   : 0x7fffffff;
        if (!__any(fv < s)) break;
        __builtin_amdgcn_s_sleep(1);
      }
      __builtin_amdgcn_sched_barrier(0);
      // 104 MFMAs: A from VGPRs, B from LDS
      #pragma unroll
      for (int kk = 0; kk < 13; ++kk) {
        const char* hp = hx + kk * 2560 + lane * 40;
        union { ull u[2]; f16x8 v; } B0, B1;
        B0.u[0] = *(const ull*)(hp);      B0.u[1] = *(const ull*)(hp + 8);
        B1.u[0] = *(const ull*)(hp + 16); B1.u[1] = *(const ull*)(hp + 24);
        #pragma unroll
        for (int t = 0; t < 4; ++t) {
          acc[t][0] = __builtin_amdgcn_mfma_f32_16x16x32_f16(af[t][kk], B0.v, acc[t][0], 0, 0, 0);
          acc[t][1] = __builtin_amdgcn_mfma_f32_16x16x32_f16(af[t][kk], B1.v, acc[t][1], 0, 0, 0);
        }
      }
    }

    __syncthreads();   // all hx reads done; next step's staging is safe

    // activations: acc[t][half][g] = gate g of unit u0+t, batch fr(+16)
    auto act = [&](const f32x4& a, const float4& p, float& c) -> unsigned short {
      float vi = a[0] + p.x, vf = a[1] + p.y, vg = a[2] + p.z, vo = a[3] + p.w;
      c = sigf(vf) * c + sigf(vi) * tanhf_(vg);
      f16 h = (f16)(sigf(vo) * tanhf_(c));
      unsigned short us = __builtin_bit_cast(unsigned short, h);
      return us ? us : RDY;   // -0.0 : exact zero, nonzero bits
    };
    ull pk0 = 0, pk1 = 0;
    #pragma unroll
    for (int t = 0; t < 4; ++t) {
      pk0 |= (ull)act(acc[t][0], g0[t], c_[t][0]) << (16 * t);
      pk1 |= (ull)act(acc[t][1], g1[t], c_[t][1]) << (16 * t);
    }
    if (ok) {
      ull* hbq = (ull*)(hB + ((size_t)d * 128 + s) * 13 * 1024) + kkp * 256 + qidx;
      AS8(hbq, pk0);         // single 8B atomic publish per half
      AS8(hbq + 128, pk1);
    }
  }
}

// ---------------- tail ----------------
__global__ __launch_bounds__(256) void tail_k(const float* __restrict__ feat,
                                              const float* __restrict__ wo,
                                              float* __restrict__ s_h,
                                              float* __restrict__ s_m)
{
  const int r = blockIdx.x;
  const int tid = threadIdx.x;
  const float* fr = feat + (size_t)r * 1024;
  float sum = 0.f;
  const int n0 = tid * 4;
  #pragma unroll
  for (int j = 0; j < 4; ++j) sum += tanhf_(fr[n0 + j]) * wo[n0 + j];
  #pragma unroll
  for (int off = 32; off > 0; off >>= 1) sum += __shfl_down(sum, off, 64);
  __shared__ float red[4];
  if ((tid & 63) == 0) red[tid >> 6] = sum;
  __syncthreads();
  if (tid == 0)       s_h[r] = red[0] + red[1];
  else if (tid == 64) s_m[r] = red[2] + red[3];
}

__global__ void score_k(const float* __restrict__ s_h, const float* __restrict__ s_m,
                        const float* __restrict__ bo, float* __restrict__ out)
{
  const int bh = blockIdx.x;
  const int m = threadIdx.x;
  out[(size_t)bh * 128 + m] = s_h[bh] + s_m[(bh & ~127) + m] + bo[0];
}

// ---------------- launch ----------------
extern "C" void kernel_launch(void* const* d_in, const int* in_sizes, int n_in,
                              void* d_out, int out_size, void* d_ws, size_t ws_size,
                              hipStream_t stream)
{
  const int*   wt   = (const int*)d_in[0];
  const int*   pt   = (const int*)d_in[2];
  const float* we   = (const float*)d_in[3];
  const float* pe   = (const float*)d_in[4];
  const float* Wih0 = (const float*)d_in[5];
  const float* Whh0 = (const float*)d_in[6];
  const float* b0   = (const float*)d_in[7];
  const float* Wih1 = (const float*)d_in[8];
  const float* Whh1 = (const float*)d_in[9];
  const float* b1   = (const float*)d_in[10];
  const float* Wh   = (const float*)d_in[11];
  const float* bh   = (const float*)d_in[12];
  const float* Wm   = (const float*)d_in[13];
  const float* bm   = (const float*)d_in[14];
  const float* Wo   = (const float*)d_in[15];
  const float* bo   = (const float*)d_in[16];
  float* out = (float*)d_out;

  char* p = (char*)d_ws;
  auto alloc = [&](size_t bytes) { char* q = p; p += (bytes + 255) & ~(size_t)255; return q; };
  f16*   x0    = (f16*)alloc((size_t)4096 * K0P * 2);
  f16*   wihr0 = (f16*)alloc((size_t)GN * K0P * 2);
  f16*   wihr1 = (f16*)alloc((size_t)GN * 800 * 2);
  f16*   whhr0 = (f16*)alloc((size_t)2 * NBLK * 256 * WKP * 2);
  f16*   whhr1 = (f16*)alloc((size_t)2 * NBLK * 256 * WKP * 2);
  f16*   whm   = (f16*)alloc((size_t)1024 * 800 * 2);
  float* biasr0= (float*)alloc(GN * 4);
  float* biasr1= (float*)alloc(GN * 4);
  float* bhm   = (float*)alloc(1024 * 4);
  float* sh    = (float*)alloc(4096 * 4);
  float* sm    = (float*)alloc(4096 * 4);
  f16*   h1    = (f16*)alloc((size_t)4096 * 800 * 2);
  f16*   h2    = (f16*)alloc((size_t)4096 * 800 * 2);
  f16*   hB    = (f16*)alloc(HB_BYTES);          // [layer][d][s][13][1024]
  float* gates = (float*)alloc((size_t)4096 * GN * 4);
  float* feat  = (float*)gates;   // gates dead before feature GEMM

  static bool attr_set = false;
  if (!attr_set) {
    hipFuncSetAttribute((const void*)lstm_mfma_k,
                        hipFuncAttributeMaxDynamicSharedMemorySize, SMEM_LSTM);
    attr_set = true;
  }

  init_hb_k<<<512, 256, 0, stream>>>((unsigned*)hB, HB_BYTES / 4);
  embed_k<<<4096, 128, 0, stream>>>(wt, pt, we, pe, x0);
  wih_reorder_k<<<1024, 256, 0, stream>>>(Wih0, b0, wihr0, biasr0, 400, K0P);
  wih_reorder_k<<<1024, 256, 0, stream>>>(Wih1, b1, wihr1, biasr1, 800, 800);
  whh_reorder_k<<<1024, 256, 0, stream>>>(Whh0, whhr0);
  whh_reorder_k<<<1024, 256, 0, stream>>>(Whh1, whhr1);
  convpad_k<<<1024, 256, 0, stream>>>(Wh, whm, 512, 800, 800);
  convpad_k<<<1024, 256, 0, stream>>>(Wm, whm + (size_t)512 * 800, 512, 800, 800);
  biascat_k<<<1, 1024, 0, stream>>>(bh, bm, bhm);

  // layer 0
  gemm_f16_nt<<<dim3(28, 32), 256, 0, stream>>>(x0, wihr0, biasr0, gates, 4096, GN, K0P);
  lstm_mfma_k<<<2 * NBLK, 256, SMEM_LSTM, stream>>>(gates, whhr0, hB);
  unpack_k<<<256, 256, 0, stream>>>(hB, h1);
  // layer 1
  gemm_f16_nt<<<dim3(28, 32), 256, 0, stream>>>(h1, wihr1, biasr1, gates, 4096, GN, 800);
  lstm_mfma_k<<<2 * NBLK, 256, SMEM_LSTM, stream>>>(gates, whhr1, hB + HB1_ELEM);
  unpack_k<<<256, 256, 0, stream>>>(hB + HB1_ELEM, h2);
  // features + scorer
  gemm_f16_nt<<<dim3(8, 32), 256, 0, stream>>>(h2, whm, bhm, feat, 4096, 1024, 800);
  tail_k<<<4096, 256, 0, stream>>>(feat, Wo, sh, sm);
  score_k<<<4096, 128, 0, stream>>>(sh, sm, bo, out);
}

// Round 16
// 1365.918 us; speedup vs baseline: 426.9902x; 1.1145x over previous
//
#include <hip/hip_runtime.h>

#define DEV __device__ __forceinline__

typedef _Float16 f16;
typedef _Float16 f16x8 __attribute__((ext_vector_type(8)));
typedef float f32x4 __attribute__((ext_vector_type(4)));
typedef unsigned long long ull;

static constexpr int K0P  = 416;   // layer0 input dim 400 padded to 13*32
static constexpr int NBLK = 13;    // blocks per direction (13*32 = 416 >= 400 units)
static constexpr int GN   = 3328;  // permuted gate cols = 2*13*128
static constexpr int WKP  = 424;   // padded K for W LDS rows (odd 16B segs -> conflict-free)
static constexpr int HX_OFF = 128 * WKP * 2;                 // 108,544 B (W)
static constexpr int FL_OFF = HX_OFF + 13 * 2560;            // hx: [13][64 lanes][4 qw], 40B/lane
static constexpr int SMEM_LSTM = FL_OFF + 16;                // 141,840 B
static constexpr int HB1_ELEM  = 2 * 128 * 13 * 1024;        // per-layer hB f16 elems
static constexpr int HB_BYTES  = 2 * HB1_ELEM * 2;           // both layers
static constexpr unsigned READY0 = 0x80008000u;              // -0.0|-0.0 : exact zero, nonzero bits

// ---------------- math helpers ----------------
DEV float sigf(float x) { return 1.f / (1.f + __expf(-x)); }
DEV float tanhf_(float x) {
  x = fminf(10.f, fmaxf(-10.f, x));
  float e = __expf(2.f * x);
  return (e - 1.f) / (e + 1.f);
}
DEV ull  AL8(const ull* p) { return __hip_atomic_load(p, __ATOMIC_RELAXED, __HIP_MEMORY_SCOPE_AGENT); }
DEV void AS4(unsigned* p, unsigned v) { __hip_atomic_store(p, v, __ATOMIC_RELAXED, __HIP_MEMORY_SCOPE_AGENT); }

// row permutation: loc in [0,128): w=loc>>5, t=(loc>>4)&1, fq=(loc>>2)&3, g=loc&3
// unit u = blk*32 + w*8 + 2*fq + t ; gate g (i,f,g,o)

// ---------------- embedding gather -> x0 f16 [4096][416] ----------------
__global__ void embed_k(const int* __restrict__ wt, const int* __restrict__ pt,
                        const float* __restrict__ we, const float* __restrict__ pe,
                        f16* __restrict__ x0)
{
  const int r = blockIdx.x;
  const int tid = threadIdx.x;
  const int w = wt[r], p = pt[r];
  const float* wrow = we + (size_t)w * 300;
  const float* prow = pe + (size_t)p * 100;
  f16* xr = x0 + (size_t)r * K0P;
  for (int k = tid; k < K0P; k += 128) {
    float v = (k < 300) ? wrow[k] : (k < 400 ? prow[k - 300] : 0.f);
    xr[k] = (f16)v;
  }
}

// ---------------- f32 -> f16 with optional K padding ----------------
__global__ void convpad_k(const float* __restrict__ src, f16* __restrict__ dst,
                          int rows, int K, int KP)
{
  const size_t total = (size_t)rows * KP;
  for (size_t i = (size_t)blockIdx.x * blockDim.x + threadIdx.x; i < total;
       i += (size_t)gridDim.x * blockDim.x) {
    int r = (int)(i / KP), k = (int)(i % KP);
    dst[i] = (f16)(k < K ? src[(size_t)r * K + k] : 0.f);
  }
}

// Wih f32 [2][1600][K] + bias -> permuted f16 [GN][KP] + biasr [GN]
__global__ void wih_reorder_k(const float* __restrict__ src, const float* __restrict__ bias,
                              f16* __restrict__ dst, float* __restrict__ biasr,
                              int K, int KP)
{
  const size_t total = (size_t)GN * KP;
  for (size_t i = (size_t)blockIdx.x * blockDim.x + threadIdx.x; i < total;
       i += (size_t)gridDim.x * blockDim.x) {
    int k = (int)(i % KP);
    int R = (int)(i / KP);
    int d = R / 1664, rr = R % 1664, blk = rr >> 7, loc = rr & 127;
    int w = loc >> 5, t = (loc >> 4) & 1, fq = (loc >> 2) & 3, g = loc & 3;
    int u = blk * 32 + w * 8 + 2 * fq + t;
    float v = (u < 400 && k < K) ? src[((size_t)d * 1600 + g * 400 + u) * K + k] : 0.f;
    dst[i] = (f16)v;
    if (k == 0) biasr[R] = (u < 400) ? bias[d * 1600 + g * 400 + u] : 0.f;
  }
}

// Whh f32 [2][1600][400] -> reordered f16 [2][NBLK][128][WKP]
__global__ void whh_reorder_k(const float* __restrict__ src, f16* __restrict__ dst)
{
  const int total = 2 * NBLK * 128 * WKP;
  for (int i = blockIdx.x * blockDim.x + threadIdx.x; i < total;
       i += gridDim.x * blockDim.x) {
    int k = i % WKP, loc = (i / WKP) & 127, blk = (i / (WKP * 128)) % NBLK,
        d = i / (WKP * 128 * NBLK);
    int w = loc >> 5, t = (loc >> 4) & 1, fq = (loc >> 2) & 3, g = loc & 3;
    int u = blk * 32 + w * 8 + 2 * fq + t;
    float v = (u < 400 && k < 400) ? src[((size_t)d * 1600 + g * 400 + u) * 400 + k] : 0.f;
    dst[i] = (f16)v;
  }
}

__global__ void biascat_k(const float* __restrict__ bh, const float* __restrict__ bm,
                          float* __restrict__ bhm)
{
  int i = threadIdx.x;
  bhm[i] = i < 512 ? bh[i] : bm[i - 512];
}

// hB init: zero real slots, READY0 in pad slots (block 12, dword ranges
// [128,256) and [384,512) within each (d,s) slab = units 400..415, never written).
__global__ void init_hb_k(unsigned* __restrict__ p, int n)
{
  for (int i = blockIdx.x * blockDim.x + threadIdx.x; i < n; i += gridDim.x * blockDim.x) {
    int off = i % (13 * 512);
    int blk = off >> 9, win = off & 511;
    bool pad = (blk == 12) && ((win >> 7) & 1);
    p[i] = pad ? READY0 : 0u;
  }
}

// ---------------- GEMM: C[M][N] = A[M][KP] * B[N][KP]^T + bias[n] ----------------
__global__ __launch_bounds__(256) void gemm_f16_nt(
    const f16* __restrict__ A, const f16* __restrict__ Bw,
    const float* __restrict__ bias, float* __restrict__ C,
    int M, int N, int KP)
{
  __shared__ __align__(16) f16 As[128][40];
  __shared__ __align__(16) f16 Bs[128][40];
  const int tid = threadIdx.x;
  const int bn = blockIdx.x, bm = blockIdx.y;
  const int lane = tid & 63, wid = tid >> 6;
  const int wr = wid >> 1, wc = wid & 1;
  const int srow = tid >> 1, shalf = tid & 1;
  const f16* Ap = A + (size_t)(bm * 128 + srow) * KP + shalf * 16;
  const f16* Bp = Bw + (size_t)(bn * 128 + srow) * KP + shalf * 16;
  const int fr = lane & 15, fq = lane >> 4;
  f32x4 acc[4][4] = {};
  for (int kt = 0; kt < KP; kt += 32) {
    __syncthreads();
    *(uint4*)&As[srow][shalf * 16]     = *(const uint4*)(Ap + kt);
    *(uint4*)&As[srow][shalf * 16 + 8] = *(const uint4*)(Ap + kt + 8);
    *(uint4*)&Bs[srow][shalf * 16]     = *(const uint4*)(Bp + kt);
    *(uint4*)&Bs[srow][shalf * 16 + 8] = *(const uint4*)(Bp + kt + 8);
    __syncthreads();
    f16x8 af[4], bf[4];
    #pragma unroll
    for (int m = 0; m < 4; ++m) af[m] = *(const f16x8*)&As[wr * 64 + m * 16 + fr][fq * 8];
    #pragma unroll
    for (int n = 0; n < 4; ++n) bf[n] = *(const f16x8*)&Bs[wc * 64 + n * 16 + fr][fq * 8];
    #pragma unroll
    for (int m = 0; m < 4; ++m)
      #pragma unroll
      for (int n = 0; n < 4; ++n)
        acc[m][n] = __builtin_amdgcn_mfma_f32_16x16x32_f16(af[m], bf[n], acc[m][n], 0, 0, 0);
  }
  #pragma unroll
  for (int n = 0; n < 4; ++n) {
    const int gn = bn * 128 + wc * 64 + n * 16 + fr;
    const float bv = bias ? bias[gn] : 0.f;
    #pragma unroll
    for (int m = 0; m < 4; ++m) {
      const size_t gm = (size_t)bm * 128 + wr * 64 + m * 16 + fq * 4;
      #pragma unroll
      for (int r = 0; r < 4; ++r)
        C[(gm + r) * (size_t)N + gn] = acc[m][n][r] + bv;
    }
  }
}

// ---------------- recurrence: 26 blocks, wave-partitioned poll + LDS share ------
// hB [d][s][blk][1024] f16 (pad slots READY0). Wave w polls only its kk-subset
// ({4,3,3,3} of 13), stages ready qwords into LDS hx, sets per-kk flag bit;
// all waves spin on the LDS flag word and feed MFMA B-fragments from LDS.
__global__ __launch_bounds__(256) void lstm_mfma_k(
    const float* __restrict__ gates,
    const f16* __restrict__ whh_r,
    f16* __restrict__ h_out,
    f16* __restrict__ hB)
{
  extern __shared__ __align__(16) char smem[];
  f16*  W_lds = (f16*)smem;                 // [128][WKP]
  char* hx    = smem + HX_OFF;              // [13][64][4 qw], 40B/lane
  int*  flags = (int*)(smem + FL_OFF);      // [2] parity words

  const int d = blockIdx.x / NBLK, blk = blockIdx.x % NBLK;
  const int tid = threadIdx.x;
  const int lane = tid & 63, w = tid >> 6;
  const int fr = lane & 15, fq = lane >> 4;

  // W slice -> LDS once
  {
    const uint4* src = (const uint4*)(whh_r + ((size_t)d * NBLK + blk) * 128 * WKP);
    uint4* dst = (uint4*)W_lds;
    for (int i = tid; i < 128 * WKP / 8; i += 256) dst[i] = src[i];
  }
  if (tid < 2) flags[tid] = 0;
  __syncthreads();

  // per-lane constants
  const int u0 = blk * 32 + w * 8 + 2 * fq;   // even; u1 = u0+1
  const bool ok = u0 < 400;
  const float* gbase0 = gates + (size_t)(fr * 128) * GN + d * 1664 + blk * 128 + w * 32;
  const float* gbase1 = gbase0 + (size_t)16 * 128 * GN;
  f16* hout0 = h_out + (size_t)(fr * 128) * 800 + d * 400;
  f16* hout1 = hout0 + (size_t)16 * 128 * 800;
  const f16* a0base = W_lds + (size_t)(w * 32 + fr) * WKP + fq * 8;
  const f16* a1base = a0base + 16 * WKP;
  f16* hb_d = hB + (size_t)d * 128 * 13 * 1024;

  const int nkk = (w == 0) ? 4 : 3;           // poll partition {4,3,3,3}
  const int kk0 = (w == 0) ? 0 : 4 + 3 * (w - 1);

  float c00 = 0.f, c01 = 0.f, c10 = 0.f, c11 = 0.f;

  for (int s = 0; s < 128; ++s) {
    const int t = d ? 127 - s : s;
    f32x4 acc00 = {}, acc01 = {}, acc10 = {}, acc11 = {};
    float4 p00, p10, p01, p11;

    if (s > 0) {
      // ---- L3 poll of my kk subset only ----
      const ull* slab = (const ull*)(hb_d + (size_t)(s - 1) * 13 * 1024) + lane * 2;
      ull q[4][4];
      const unsigned full = (1u << nkk) - 1;
      unsigned pend = (nkk == 4) ? 0xFFFFu : 0x0FFFu;
      unsigned wrote = 0, flagged = 0;
      int* fw = &flags[s & 1];
      while (flagged != full) {
        #pragma unroll
        for (int i = 0; i < 4; ++i)
          if (i < nkk) {
            const ull* pp = slab + (kk0 + i) * 256;
            if ((pend >> (i * 4 + 0)) & 1) q[i][0] = AL8(pp);
            if ((pend >> (i * 4 + 1)) & 1) q[i][1] = AL8(pp + 1);
            if ((pend >> (i * 4 + 2)) & 1) q[i][2] = AL8(pp + 128);
            if ((pend >> (i * 4 + 3)) & 1) q[i][3] = AL8(pp + 129);
          }
        __builtin_amdgcn_sched_barrier(0);   // keep loads issued before checks
        #pragma unroll
        for (int i = 0; i < 4; ++i)
          if (i < nkk)
            #pragma unroll
            for (int j = 0; j < 4; ++j)
              if ((pend >> (i * 4 + j)) & 1) {
                ull v = q[i][j];
                if ((unsigned)v != 0u && (unsigned)(v >> 32) != 0u)
                  pend &= ~(1u << (i * 4 + j));
              }
        // stage completed kks into LDS
        #pragma unroll
        for (int i = 0; i < 4; ++i)
          if (i < nkk && !((wrote >> i) & 1) && ((pend >> (i * 4)) & 15u) == 0u) {
            char* hp = hx + (kk0 + i) * 2560 + lane * 40;
            *(ull*)(hp +  0) = q[i][0];
            *(ull*)(hp +  8) = q[i][1];
            *(ull*)(hp + 16) = q[i][2];
            *(ull*)(hp + 24) = q[i][3];
            wrote |= 1u << i;
          }
        // publish per-kk flags once the whole wave's slice is staged
        #pragma unroll
        for (int i = 0; i < 4; ++i)
          if (i < nkk && !((flagged >> i) & 1)) {
            bool done = ((pend >> (i * 4)) & 15u) == 0u;
            if (__all(done)) {
              asm volatile("s_waitcnt lgkmcnt(0)" ::: "memory");
              if (lane == 0)
                __hip_atomic_fetch_or(fw, 1 << (kk0 + i), __ATOMIC_RELAXED,
                                      __HIP_MEMORY_SCOPE_WORKGROUP);
              flagged |= 1u << i;
            }
          }
        if (flagged != full) __builtin_amdgcn_s_sleep(2);
      }
      // gate prefetch: flies under the LDS spin + MFMA
      const float* g0 = gbase0 + (size_t)t * GN;
      const float* g1 = gbase1 + (size_t)t * GN;
      p00 = *(const float4*)(g0 + fq * 4);
      p10 = *(const float4*)(g0 + 16 + fq * 4);
      p01 = *(const float4*)(g1 + fq * 4);
      p11 = *(const float4*)(g1 + 16 + fq * 4);
      // wait for all 13 kk staged (intra-CU spin, acquire)
      while ((__hip_atomic_load(fw, __ATOMIC_ACQUIRE, __HIP_MEMORY_SCOPE_WORKGROUP)
              & 0x1FFF) != 0x1FFF)
        __builtin_amdgcn_s_sleep(1);
      __builtin_amdgcn_sched_barrier(0);
      // MFMA with B-fragments from LDS
      #pragma unroll
      for (int kk = 0; kk < 13; ++kk) {
        const char* hp = hx + kk * 2560 + lane * 40;
        f16x8 a0 = *(const f16x8*)(a0base + kk * 32);
        f16x8 a1 = *(const f16x8*)(a1base + kk * 32);
        union { ull u[2]; f16x8 v; } B0, B1;
        B0.u[0] = *(const ull*)(hp);      B0.u[1] = *(const ull*)(hp + 8);
        B1.u[0] = *(const ull*)(hp + 16); B1.u[1] = *(const ull*)(hp + 24);
        acc00 = __builtin_amdgcn_mfma_f32_16x16x32_f16(a0, B0.v, acc00, 0, 0, 0);
        acc01 = __builtin_amdgcn_mfma_f32_16x16x32_f16(a0, B1.v, acc01, 0, 0, 0);
        acc10 = __builtin_amdgcn_mfma_f32_16x16x32_f16(a1, B0.v, acc10, 0, 0, 0);
        acc11 = __builtin_amdgcn_mfma_f32_16x16x32_f16(a1, B1.v, acc11, 0, 0, 0);
      }
    } else {
      const float* g0 = gbase0 + (size_t)t * GN;
      const float* g1 = gbase1 + (size_t)t * GN;
      p00 = *(const float4*)(g0 + fq * 4);
      p10 = *(const float4*)(g0 + 16 + fq * 4);
      p01 = *(const float4*)(g1 + fq * 4);
      p11 = *(const float4*)(g1 + 16 + fq * 4);
    }

    __syncthreads();                       // all hx reads done; safe to reuse next step
    if (tid == 0)
      __hip_atomic_store(&flags[s & 1], 0, __ATOMIC_RELAXED, __HIP_MEMORY_SCOPE_WORKGROUP);

    // in-register activations: acc reg r = gate r (i,f,g,o) of one unit
    auto act = [&](const f32x4& a, const float4& p, float& c) -> f16 {
      float vi = a[0] + p.x, vf = a[1] + p.y, vg = a[2] + p.z, vo = a[3] + p.w;
      c = sigf(vf) * c + sigf(vi) * tanhf_(vg);
      return (f16)(sigf(vo) * tanhf_(c));
    };
    f16 h00 = act(acc00, p00, c00);   // (u0,   batch fr)
    f16 h10 = act(acc10, p10, c10);   // (u0+1, batch fr)
    f16 h01 = act(acc01, p01, c01);   // (u0,   batch fr+16)
    f16 h11 = act(acc11, p11, c11);   // (u0+1, batch fr+16)

    if (ok) {
      unsigned pk0 = (unsigned)__builtin_bit_cast(unsigned short, h00) |
                     ((unsigned)__builtin_bit_cast(unsigned short, h10) << 16);
      unsigned pk1 = (unsigned)__builtin_bit_cast(unsigned short, h01) |
                     ((unsigned)__builtin_bit_cast(unsigned short, h11) << 16);
      if (pk0 == 0u) pk0 = READY0;   // -0|-0: numerically exact zero, nonzero bits
      if (pk1 == 0u) pk1 = READY0;
      unsigned* hbw = (unsigned*)(hb_d + (size_t)s * 13 * 1024 + blk * 1024
                                  + (w * 16 + fr) * 8) + fq;
      AS4(hbw, pk0);          // publish: store flight is the only handoff latency
      AS4(hbw + 256, pk1);
      *(unsigned*)(hout0 + (size_t)t * 800 + u0) = pk0;   // row-major for next GEMM
      *(unsigned*)(hout1 + (size_t)t * 800 + u0) = pk1;
    }
  }
}

// ---------------- tail ----------------
__global__ __launch_bounds__(256) void tail_k(const float* __restrict__ feat,
                                              const float* __restrict__ wo,
                                              float* __restrict__ s_h,
                                              float* __restrict__ s_m)
{
  const int r = blockIdx.x;
  const int tid = threadIdx.x;
  const float* fr = feat + (size_t)r * 1024;
  float sum = 0.f;
  const int n0 = tid * 4;
  #pragma unroll
  for (int j = 0; j < 4; ++j) sum += tanhf_(fr[n0 + j]) * wo[n0 + j];
  #pragma unroll
  for (int off = 32; off > 0; off >>= 1) sum += __shfl_down(sum, off, 64);
  __shared__ float red[4];
  if ((tid & 63) == 0) red[tid >> 6] = sum;
  __syncthreads();
  if (tid == 0)       s_h[r] = red[0] + red[1];
  else if (tid == 64) s_m[r] = red[2] + red[3];
}

__global__ void score_k(const float* __restrict__ s_h, const float* __restrict__ s_m,
                        const float* __restrict__ bo, float* __restrict__ out)
{
  const int bh = blockIdx.x;
  const int m = threadIdx.x;
  out[(size_t)bh * 128 + m] = s_h[bh] + s_m[(bh & ~127) + m] + bo[0];
}

// ---------------- launch ----------------
extern "C" void kernel_launch(void* const* d_in, const int* in_sizes, int n_in,
                              void* d_out, int out_size, void* d_ws, size_t ws_size,
                              hipStream_t stream)
{
  const int*   wt   = (const int*)d_in[0];
  const int*   pt   = (const int*)d_in[2];
  const float* we   = (const float*)d_in[3];
  const float* pe   = (const float*)d_in[4];
  const float* Wih0 = (const float*)d_in[5];
  const float* Whh0 = (const float*)d_in[6];
  const float* b0   = (const float*)d_in[7];
  const float* Wih1 = (const float*)d_in[8];
  const float* Whh1 = (const float*)d_in[9];
  const float* b1   = (const float*)d_in[10];
  const float* Wh   = (const float*)d_in[11];
  const float* bh   = (const float*)d_in[12];
  const float* Wm   = (const float*)d_in[13];
  const float* bm   = (const float*)d_in[14];
  const float* Wo   = (const float*)d_in[15];
  const float* bo   = (const float*)d_in[16];
  float* out = (float*)d_out;

  char* p = (char*)d_ws;
  auto alloc = [&](size_t bytes) { char* q = p; p += (bytes + 255) & ~(size_t)255; return q; };
  f16*   x0    = (f16*)alloc((size_t)4096 * K0P * 2);
  f16*   wihr0 = (f16*)alloc((size_t)GN * K0P * 2);
  f16*   wihr1 = (f16*)alloc((size_t)GN * 800 * 2);
  f16*   whhr0 = (f16*)alloc((size_t)2 * NBLK * 128 * WKP * 2);
  f16*   whhr1 = (f16*)alloc((size_t)2 * NBLK * 128 * WKP * 2);
  f16*   whm   = (f16*)alloc((size_t)1024 * 800 * 2);
  float* biasr0= (float*)alloc(GN * 4);
  float* biasr1= (float*)alloc(GN * 4);
  float* bhm   = (float*)alloc(1024 * 4);
  float* sh    = (float*)alloc(4096 * 4);
  float* sm    = (float*)alloc(4096 * 4);
  f16*   h1    = (f16*)alloc((size_t)4096 * 800 * 2);
  f16*   h2    = (f16*)alloc((size_t)4096 * 800 * 2);
  f16*   hB    = (f16*)alloc(HB_BYTES);          // [layer][d][s][blk][1024]
  float* gates = (float*)alloc((size_t)4096 * GN * 4);
  float* feat  = (float*)gates;   // gates dead before feature GEMM

  static bool attr_set = false;
  if (!attr_set) {
    hipFuncSetAttribute((const void*)lstm_mfma_k,
                        hipFuncAttributeMaxDynamicSharedMemorySize, SMEM_LSTM);
    attr_set = true;
  }

  // hB: zero real slots, READY0 only in never-written pad slots
  init_hb_k<<<512, 256, 0, stream>>>((unsigned*)hB, HB_BYTES / 4);
  embed_k<<<4096, 128, 0, stream>>>(wt, pt, we, pe, x0);
  wih_reorder_k<<<1024, 256, 0, stream>>>(Wih0, b0, wihr0, biasr0, 400, K0P);
  wih_reorder_k<<<1024, 256, 0, stream>>>(Wih1, b1, wihr1, biasr1, 800, 800);
  whh_reorder_k<<<1024, 256, 0, stream>>>(Whh0, whhr0);
  whh_reorder_k<<<1024, 256, 0, stream>>>(Whh1, whhr1);
  convpad_k<<<1024, 256, 0, stream>>>(Wh, whm, 512, 800, 800);
  convpad_k<<<1024, 256, 0, stream>>>(Wm, whm + (size_t)512 * 800, 512, 800, 800);
  biascat_k<<<1, 1024, 0, stream>>>(bh, bm, bhm);

  // layer 0
  gemm_f16_nt<<<dim3(26, 32), 256, 0, stream>>>(x0, wihr0, biasr0, gates, 4096, GN, K0P);
  lstm_mfma_k<<<26, 256, SMEM_LSTM, stream>>>(gates, whhr0, h1, hB);
  // layer 1
  gemm_f16_nt<<<dim3(26, 32), 256, 0, stream>>>(h1, wihr1, biasr1, gates, 4096, GN, 800);
  lstm_mfma_k<<<26, 256, SMEM_LSTM, stream>>>(gates, whhr1, h2, hB + HB1_ELEM);
  // features + scorer
  gemm_f16_nt<<<dim3(8, 32), 256, 0, stream>>>(h2, whm, bhm, feat, 4096, 1024, 800);
  tail_k<<<4096, 256, 0, stream>>>(feat, Wo, sh, sm);
  score_k<<<4096, 128, 0, stream>>>(sh, sm, bo, out);
}